// Round 1
// baseline (430.738 us; speedup 1.0000x reference)
//
#include <hip/hip_runtime.h>
#include <hip/hip_bf16.h>

#define NB 512
#define NS 200
#define NK 16
#define NH 256
#define INV_SQRT_H 0.0625f
#define EPS_LN 1e-12f
#define EPS_COS 1e-6f

typedef __attribute__((ext_vector_type(8))) short bf16x8;
typedef __attribute__((ext_vector_type(4))) float f32x4;

__device__ __forceinline__ float wred_sum(float v) {
    v += __shfl_xor(v, 1);  v += __shfl_xor(v, 2);  v += __shfl_xor(v, 4);
    v += __shfl_xor(v, 8);  v += __shfl_xor(v, 16); v += __shfl_xor(v, 32);
    return v;
}

__device__ __forceinline__ float block_sum256(float v, float* scr) {
    v = wred_sum(v);
    int w = threadIdx.x >> 6;
    __syncthreads();
    if ((threadIdx.x & 63) == 0) scr[w] = v;
    __syncthreads();
    return scr[0] + scr[1] + scr[2] + scr[3];
}

// ---------------- Kernel 1: prototypes LN2 + norm -> pn_div[k][h] ----------------
__global__ void k_prep_protos(const float* __restrict__ prot,
                              const float* __restrict__ w2, const float* __restrict__ b2,
                              float* __restrict__ pn_div) {
    __shared__ float scr[4];
    int t = threadIdx.x;
    for (int k = 0; k < NK; ++k) {
        float x  = prot[k * NH + t];
        float u  = block_sum256(x, scr) * (1.f / NH);
        float d  = x - u;
        float s2 = block_sum256(d * d, scr) * (1.f / NH);
        float pn = w2[t] * d * rsqrtf(s2 + EPS_LN) + b2[t];
        float nsq = block_sum256(pn * pn, scr);
        float pinv = 1.f / fmaxf(sqrtf(nsq), EPS_COS);
        pn_div[k * NH + t] = pn * pinv;
    }
}

// ---------------- Kernel 2: query = LN4(b' + alphas[-1] + z[:,-1,:]) ----------------
__global__ void k_query(const float* __restrict__ z, const float* __restrict__ b_prime,
                        const float* __restrict__ alphas,
                        const float* __restrict__ w4, const float* __restrict__ b4,
                        float* __restrict__ q) {
    __shared__ float scr[4];
    int t = threadIdx.x;
    int b = blockIdx.x;
    float x = b_prime[t] + alphas[(NS - 1) * NH + t] + z[((size_t)b * NS + (NS - 1)) * NH + t];
    float u = block_sum256(x, scr) * (1.f / NH);
    float d = x - u;
    float var = block_sum256(d * d, scr) * (1.f / NH);
    q[b * NH + t] = w4[t] * d * rsqrtf(var + EPS_LN) + b4[t];
}

// ---------------- Kernel 2b: cast W to bf16 ----------------
__global__ void k_castw(const float* __restrict__ w, __hip_bfloat16* __restrict__ w_bf) {
    int i = (blockIdx.x * 256 + threadIdx.x) * 4;
#pragma unroll
    for (int j = 0; j < 4; ++j) w_bf[i + j] = __float2bfloat16(w[i + j]);
}

// ---------------- Kernel 3: per-row pass: p_k_i + kt(bf16). One wave per row. ----------------
__global__ void k_rows(const float* __restrict__ z, const float* __restrict__ pn_div,
                       const float* __restrict__ ln1w, const float* __restrict__ ln1b,
                       const float* __restrict__ ln3w, const float* __restrict__ ln3b,
                       const float* __restrict__ alphas,
                       float* __restrict__ p_k_i, __hip_bfloat16* __restrict__ kt) {
    int lane = threadIdx.x & 63;
    int wave = threadIdx.x >> 6;
    int row  = blockIdx.x * 4 + wave;          // < NB*NS
    int s    = row % NS;
    size_t base = (size_t)row * NH;

    float zv[4];
#pragma unroll
    for (int j = 0; j < 4; ++j) zv[j] = z[base + lane + 64 * j];

    // LN1
    float sm = 0.f, sq = 0.f;
#pragma unroll
    for (int j = 0; j < 4; ++j) { sm += zv[j]; sq += zv[j] * zv[j]; }
    sm = wred_sum(sm); sq = wred_sum(sq);
    float u    = sm * (1.f / NH);
    float var  = sq * (1.f / NH) - u * u;
    float rstd = rsqrtf(var + EPS_LN);

    float zn[4]; float nsq = 0.f;
#pragma unroll
    for (int j = 0; j < 4; ++j) {
        int h = lane + 64 * j;
        zn[j] = ln1w[h] * (zv[j] - u) * rstd + ln1b[h];
        nsq += zn[j] * zn[j];
    }
    nsq = wred_sum(nsq);
    float inv_zn = 1.f / fmaxf(sqrtf(nsq), EPS_COS);

    // 16 dot products vs prototypes
    float acc[NK];
#pragma unroll
    for (int k = 0; k < NK; ++k) acc[k] = 0.f;
#pragma unroll
    for (int j = 0; j < 4; ++j) {
        int h = lane + 64 * j;
        float zj = zn[j];
#pragma unroll
        for (int k = 0; k < NK; ++k) acc[k] += zj * pn_div[k * NH + h];
    }
#pragma unroll
    for (int k = 0; k < NK; ++k) {
#pragma unroll
        for (int m = 1; m < 64; m <<= 1) acc[k] += __shfl_xor(acc[k], m);
    }
    // softmax over K (all lanes redundantly)
    float l[NK]; float mx = -1e30f;
#pragma unroll
    for (int k = 0; k < NK; ++k) { l[k] = acc[k] * inv_zn * INV_SQRT_H; mx = fmaxf(mx, l[k]); }
    float e[NK]; float se = 0.f;
#pragma unroll
    for (int k = 0; k < NK; ++k) { e[k] = __expf(l[k] - mx); se += e[k]; }
    float inv_se = 1.f / se;
    float myp = 0.f;
#pragma unroll
    for (int k = 0; k < NK; ++k) if (lane == k) myp = e[k] * inv_se;
    if (lane < NK) p_k_i[(size_t)row * NK + lane] = myp;

    // keys_tilde = LN3(z + alphas[s])
    float xv[4];
    sm = 0.f; sq = 0.f;
#pragma unroll
    for (int j = 0; j < 4; ++j) {
        xv[j] = zv[j] + alphas[s * NH + lane + 64 * j];
        sm += xv[j]; sq += xv[j] * xv[j];
    }
    sm = wred_sum(sm); sq = wred_sum(sq);
    float u3 = sm * (1.f / NH);
    float v3 = sq * (1.f / NH) - u3 * u3;
    float r3 = rsqrtf(v3 + EPS_LN);
#pragma unroll
    for (int j = 0; j < 4; ++j) {
        int h = lane + 64 * j;
        kt[base + h] = __float2bfloat16(ln3w[h] * (xv[j] - u3) * r3 + ln3b[h]);
    }
}

// ---------------- Kernel 4: MFMA GEMM kt@W^T + relu + scores ----------------
// 64 rows per block, 4 waves x 64 cols each. Fragments direct from global (L2-hot).
__global__ __launch_bounds__(256) void k_gemm_scores(
        const __hip_bfloat16* __restrict__ kt, const __hip_bfloat16* __restrict__ w_bf,
        const float* __restrict__ w_bias, const float* __restrict__ q,
        float* __restrict__ scores) {
    __shared__ float sc[4][64];
    int tid = threadIdx.x, wave = tid >> 6, lane = tid & 63;
    int g = lane >> 4, c = lane & 15;
    int row0 = blockIdx.x * 64;
    int n_base = wave * 64;

    f32x4 acc[4][4];
#pragma unroll
    for (int mf = 0; mf < 4; ++mf)
#pragma unroll
        for (int nf = 0; nf < 4; ++nf) { f32x4 zz = {0.f, 0.f, 0.f, 0.f}; acc[mf][nf] = zz; }

#pragma unroll
    for (int ks = 0; ks < 8; ++ks) {
        bf16x8 a[4], bb[4];
#pragma unroll
        for (int mf = 0; mf < 4; ++mf)
            a[mf] = *reinterpret_cast<const bf16x8*>(
                kt + (size_t)(row0 + mf * 16 + c) * NH + ks * 32 + g * 8);
#pragma unroll
        for (int nf = 0; nf < 4; ++nf)
            bb[nf] = *reinterpret_cast<const bf16x8*>(
                w_bf + (size_t)(n_base + nf * 16 + c) * NH + ks * 32 + g * 8);
#pragma unroll
        for (int mf = 0; mf < 4; ++mf)
#pragma unroll
            for (int nf = 0; nf < 4; ++nf)
                acc[mf][nf] = __builtin_amdgcn_mfma_f32_16x16x32_bf16(a[mf], bb[nf], acc[mf][nf], 0, 0, 0);
    }

    // epilogue: score_row += sum_n (kt + relu(u + bias)) * q[b]
#pragma unroll
    for (int mf = 0; mf < 4; ++mf) {
#pragma unroll
        for (int r = 0; r < 4; ++r) {
            int m = mf * 16 + g * 4 + r;
            int row = row0 + m;
            int bb2 = row / NS;
            float partial = 0.f;
#pragma unroll
            for (int nf = 0; nf < 4; ++nf) {
                int n = n_base + nf * 16 + c;
                float uval = acc[mf][nf][r] + w_bias[n];
                float key = __bfloat162float(kt[(size_t)row * NH + n]) + fmaxf(uval, 0.f);
                partial += key * q[bb2 * NH + n];
            }
            partial += __shfl_xor(partial, 1, 16);
            partial += __shfl_xor(partial, 2, 16);
            partial += __shfl_xor(partial, 4, 16);
            partial += __shfl_xor(partial, 8, 16);
            if (c == 0) sc[wave][m] = partial;
        }
    }
    __syncthreads();
    if (tid < 64) scores[row0 + tid] = sc[0][tid] + sc[1][tid] + sc[2][tid] + sc[3][tid];
}

// ---------------- Kernel 5: softmax over S, aggregate, LN5 ----------------
__global__ void k_final(const float* __restrict__ z, const float* __restrict__ scores,
                        const float* __restrict__ p_k_i,
                        const float* __restrict__ beta_in, const float* __restrict__ beta_lb,
                        const int* __restrict__ flag,
                        const float* __restrict__ ln5w, const float* __restrict__ ln5b,
                        float* __restrict__ out) {
    __shared__ float p_i[NS];
    __shared__ float attn[NS * NK];
    __shared__ float enc[NK * NH];
    int tid = threadIdx.x, lane = tid & 63, wave = tid >> 6;
    int b = blockIdx.x;

    if (wave == 0) {
        float l[4]; float mx = -1e30f;
#pragma unroll
        for (int j = 0; j < 4; ++j) {
            int s = lane + 64 * j;
            l[j] = (s < NS) ? scores[b * NS + s] * INV_SQRT_H : -1e30f;
            mx = fmaxf(mx, l[j]);
        }
#pragma unroll
        for (int m = 1; m < 64; m <<= 1) mx = fmaxf(mx, __shfl_xor(mx, m));
        float ev[4]; float se = 0.f;
#pragma unroll
        for (int j = 0; j < 4; ++j) {
            int s = lane + 64 * j;
            ev[j] = (s < NS) ? __expf(l[j] - mx) : 0.f;
            se += ev[j];
        }
        se = wred_sum(se);
        float inv = 1.f / se;
#pragma unroll
        for (int j = 0; j < 4; ++j) {
            int s = lane + 64 * j;
            if (s < NS) p_i[s] = ev[j] * inv;
        }
    }
    __syncthreads();
    for (int idx = tid; idx < NS * NK; idx += 256)
        attn[idx] = p_k_i[(size_t)b * NS * NK + idx] * p_i[idx >> 4];
    __syncthreads();

    const float* beta = (*flag) ? beta_in : beta_lb;
    float acc[NK];
#pragma unroll
    for (int k = 0; k < NK; ++k) acc[k] = beta[k * NH + tid];
    for (int s = 0; s < NS; ++s) {
        float zv = z[((size_t)b * NS + s) * NH + tid];
#pragma unroll
        for (int k = 0; k < NK; ++k) acc[k] += attn[s * NK + k] * zv;
    }
#pragma unroll
    for (int k = 0; k < NK; ++k) enc[k * NH + tid] = acc[k];
    __syncthreads();

#pragma unroll
    for (int i = 0; i < 4; ++i) {
        int k = wave * 4 + i;
        float e[4], sm = 0.f, sq = 0.f;
#pragma unroll
        for (int j = 0; j < 4; ++j) {
            e[j] = enc[k * NH + lane + 64 * j];
            sm += e[j]; sq += e[j] * e[j];
        }
        sm = wred_sum(sm); sq = wred_sum(sq);
        float u = sm * (1.f / NH);
        float var = sq * (1.f / NH) - u * u;
        float rstd = rsqrtf(var + EPS_LN);
#pragma unroll
        for (int j = 0; j < 4; ++j) {
            int h = lane + 64 * j;
            out[((size_t)b * NK + k) * NH + h] = ln5w[h] * (e[j] - u) * rstd + ln5b[h];
        }
    }
}

extern "C" void kernel_launch(void* const* d_in, const int* in_sizes, int n_in,
                              void* d_out, int out_size, void* d_ws, size_t ws_size,
                              hipStream_t stream) {
    const float* z        = (const float*)d_in[0];
    const float* prot     = (const float*)d_in[1];
    const float* ln1w     = (const float*)d_in[2];
    const float* ln1b     = (const float*)d_in[3];
    const float* ln2w     = (const float*)d_in[4];
    const float* ln2b     = (const float*)d_in[5];
    const float* ln3w     = (const float*)d_in[6];
    const float* ln3b     = (const float*)d_in[7];
    const float* ln4w     = (const float*)d_in[8];
    const float* ln4b     = (const float*)d_in[9];
    const float* ln5w     = (const float*)d_in[10];
    const float* ln5b     = (const float*)d_in[11];
    const float* w_weight = (const float*)d_in[12];
    const float* w_bias   = (const float*)d_in[13];
    const float* b_prime  = (const float*)d_in[14];
    const float* alphas   = (const float*)d_in[15];
    const float* beta_in  = (const float*)d_in[16];
    const float* beta_lb  = (const float*)d_in[17];
    const int*   flag     = (const int*)d_in[18];
    float* out = (float*)d_out;

    char* ws = (char*)d_ws;
    float*          pn_div = (float*)(ws);                       // 16 KB
    float*          q      = (float*)(ws + 16384);               // 512 KB
    __hip_bfloat16* w_bf   = (__hip_bfloat16*)(ws + 540672);     // 128 KB
    float*          p_k_i  = (float*)(ws + 671744);              // 6.55 MB
    float*          scores = (float*)(ws + 7225344);             // 410 KB
    __hip_bfloat16* kt     = (__hip_bfloat16*)(ws + 7634944);    // 52.4 MB

    k_prep_protos<<<1, 256, 0, stream>>>(prot, ln2w, ln2b, pn_div);
    k_query<<<NB, 256, 0, stream>>>(z, b_prime, alphas, ln4w, ln4b, q);
    k_castw<<<64, 256, 0, stream>>>(w_weight, w_bf);
    k_rows<<<NB * NS / 4, 256, 0, stream>>>(z, pn_div, ln1w, ln1b, ln3w, ln3b, alphas, p_k_i, kt);
    k_gemm_scores<<<NB * NS / 64, 256, 0, stream>>>(kt, w_bf, w_bias, q, scores);
    k_final<<<NB, 256, 0, stream>>>(z, scores, p_k_i, beta_in, beta_lb, flag, ln5w, ln5b, out);
}

// Round 2
// 357.606 us; speedup vs baseline: 1.2045x; 1.2045x over previous
//
#include <hip/hip_runtime.h>
#include <hip/hip_bf16.h>

#define NB 512
#define NS 200
#define NK 16
#define NH 256
#define INV_SQRT_H 0.0625f
#define EPS_LN 1e-12f
#define EPS_COS 1e-6f

typedef __attribute__((ext_vector_type(8))) short bf16x8;
typedef __attribute__((ext_vector_type(4))) short s16x4;
typedef __attribute__((ext_vector_type(4))) float f32x4;

__device__ __forceinline__ float wred_sum(float v) {
    v += __shfl_xor(v, 1);  v += __shfl_xor(v, 2);  v += __shfl_xor(v, 4);
    v += __shfl_xor(v, 8);  v += __shfl_xor(v, 16); v += __shfl_xor(v, 32);
    return v;
}

__device__ __forceinline__ float block_sum256(float v, float* scr) {
    v = wred_sum(v);
    int w = threadIdx.x >> 6;
    __syncthreads();
    if ((threadIdx.x & 63) == 0) scr[w] = v;
    __syncthreads();
    return scr[0] + scr[1] + scr[2] + scr[3];
}

// ---------------- Kernel 1 (merged prep): protos LN2+norm | cast W | query LN4 ----------------
__global__ __launch_bounds__(256) void k_prep(
        const float* __restrict__ prot, const float* __restrict__ w2, const float* __restrict__ b2,
        const float* __restrict__ w_weight, __hip_bfloat16* __restrict__ w_bf,
        const float* __restrict__ z, const float* __restrict__ b_prime,
        const float* __restrict__ alphas, const float* __restrict__ w4, const float* __restrict__ b4,
        float* __restrict__ pn_div, float* __restrict__ q) {
    __shared__ float scr[4];
    int t = threadIdx.x;
    int bid = blockIdx.x;
    if (bid == 0) {
        for (int k = 0; k < NK; ++k) {
            float x  = prot[k * NH + t];
            float u  = block_sum256(x, scr) * (1.f / NH);
            float d  = x - u;
            float s2 = block_sum256(d * d, scr) * (1.f / NH);
            float pn = w2[t] * d * rsqrtf(s2 + EPS_LN) + b2[t];
            float nsq = block_sum256(pn * pn, scr);
            float pinv = 1.f / fmaxf(sqrtf(nsq), EPS_COS);
            pn_div[k * NH + t] = pn * pinv;
        }
    } else if (bid <= 64) {
        int i = ((bid - 1) * 256 + t) * 4;
        f32x4 w = *reinterpret_cast<const f32x4*>(w_weight + i);
        union { s16x4 v; __hip_bfloat16 h[4]; } u;
#pragma unroll
        for (int j = 0; j < 4; ++j) u.h[j] = __float2bfloat16(w[j]);
        *reinterpret_cast<s16x4*>(w_bf + i) = u.v;
    } else {
        int b = bid - 65;
        float x = b_prime[t] + alphas[(NS - 1) * NH + t] + z[((size_t)b * NS + (NS - 1)) * NH + t];
        float u = block_sum256(x, scr) * (1.f / NH);
        float d = x - u;
        float var = block_sum256(d * d, scr) * (1.f / NH);
        q[b * NH + t] = w4[t] * d * rsqrtf(var + EPS_LN) + b4[t];
    }
}

// ---------------- Kernel 2: per-row pass: p_k_i + kt(bf16). One wave per row, float4. ----------------
__global__ __launch_bounds__(256) void k_rows(
        const float* __restrict__ z, const float* __restrict__ pn_div,
        const float* __restrict__ ln1w, const float* __restrict__ ln1b,
        const float* __restrict__ ln3w, const float* __restrict__ ln3b,
        const float* __restrict__ alphas,
        float* __restrict__ p_k_i, __hip_bfloat16* __restrict__ kt) {
    int lane = threadIdx.x & 63;
    int wave = threadIdx.x >> 6;
    int row  = blockIdx.x * 4 + wave;          // < NB*NS
    int s    = row % NS;
    size_t base = (size_t)row * NH;
    int h0 = lane * 4;

    f32x4 zv = *reinterpret_cast<const f32x4*>(z + base + h0);
    f32x4 av = *reinterpret_cast<const f32x4*>(alphas + s * NH + h0);
    f32x4 w1 = *reinterpret_cast<const f32x4*>(ln1w + h0);
    f32x4 b1 = *reinterpret_cast<const f32x4*>(ln1b + h0);
    f32x4 w3 = *reinterpret_cast<const f32x4*>(ln3w + h0);
    f32x4 b3 = *reinterpret_cast<const f32x4*>(ln3b + h0);

    // ---- LN1 ----
    float sm = zv[0] + zv[1] + zv[2] + zv[3];
    float sq = zv[0]*zv[0] + zv[1]*zv[1] + zv[2]*zv[2] + zv[3]*zv[3];
    sm = wred_sum(sm); sq = wred_sum(sq);
    float u    = sm * (1.f / NH);
    float var  = sq * (1.f / NH) - u * u;
    float rstd = rsqrtf(var + EPS_LN);

    f32x4 zn;
    float nsq = 0.f;
#pragma unroll
    for (int j = 0; j < 4; ++j) { zn[j] = w1[j] * (zv[j] - u) * rstd + b1[j]; nsq += zn[j] * zn[j]; }
    nsq = wred_sum(nsq);
    float inv_zn = 1.f / fmaxf(sqrtf(nsq), EPS_COS);

    // ---- 16 prototype dot products (per-lane partials) ----
    float acc[NK];
#pragma unroll
    for (int k = 0; k < NK; ++k) {
        f32x4 p = *reinterpret_cast<const f32x4*>(pn_div + k * NH + h0);
        acc[k] = zn[0]*p[0] + zn[1]*p[1] + zn[2]*p[2] + zn[3]*p[3];
    }
    // ---- packed butterfly: lane ends with total for k = lane & 15 ----
#pragma unroll
    for (int r = 0; r < 4; ++r) {
        int m = 1 << r;
        int n = NK >> r;
        bool hi = (lane & m) != 0;
#pragma unroll
        for (int i = 0; i < 8; ++i) {
            if (i < n / 2) {
                float a = acc[2 * i], b = acc[2 * i + 1];
                float x = hi ? a : b;
                float y = __shfl_xor(x, m);
                acc[i] = (hi ? b : a) + y;
            }
        }
    }
    acc[0] += __shfl_xor(acc[0], 16);
    acc[0] += __shfl_xor(acc[0], 32);

    // ---- softmax over 16-lane group ----
    float logit = acc[0] * inv_zn * INV_SQRT_H;
    float mx = logit;
    mx = fmaxf(mx, __shfl_xor(mx, 1)); mx = fmaxf(mx, __shfl_xor(mx, 2));
    mx = fmaxf(mx, __shfl_xor(mx, 4)); mx = fmaxf(mx, __shfl_xor(mx, 8));
    float e = __expf(logit - mx);
    float se = e;
    se += __shfl_xor(se, 1); se += __shfl_xor(se, 2);
    se += __shfl_xor(se, 4); se += __shfl_xor(se, 8);
    if (lane < NK) p_k_i[(size_t)row * NK + lane] = e / se;

    // ---- keys_tilde = LN3(z + alphas[s]) -> bf16 ----
    f32x4 xv = zv + av;
    sm = xv[0] + xv[1] + xv[2] + xv[3];
    sq = xv[0]*xv[0] + xv[1]*xv[1] + xv[2]*xv[2] + xv[3]*xv[3];
    sm = wred_sum(sm); sq = wred_sum(sq);
    float u3 = sm * (1.f / NH);
    float v3 = sq * (1.f / NH) - u3 * u3;
    float r3 = rsqrtf(v3 + EPS_LN);
    union { s16x4 v; __hip_bfloat16 h[4]; } kv;
#pragma unroll
    for (int j = 0; j < 4; ++j) kv.h[j] = __float2bfloat16(w3[j] * (xv[j] - u3) * r3 + b3[j]);
    *reinterpret_cast<s16x4*>(kt + base + h0) = kv.v;
}

// ---------------- Kernel 3: MFMA GEMM kt@W^T + relu + scores ----------------
__global__ __launch_bounds__(256) void k_gemm_scores(
        const __hip_bfloat16* __restrict__ kt, const __hip_bfloat16* __restrict__ w_bf,
        const float* __restrict__ w_bias, const float* __restrict__ q,
        float* __restrict__ scores) {
    __shared__ float sc[4][64];
    int tid = threadIdx.x, wave = tid >> 6, lane = tid & 63;
    int g = lane >> 4, c = lane & 15;
    int row0 = blockIdx.x * 64;
    int n_base = wave * 64;

    f32x4 acc[4][4];
#pragma unroll
    for (int mf = 0; mf < 4; ++mf)
#pragma unroll
        for (int nf = 0; nf < 4; ++nf) { f32x4 zz = {0.f, 0.f, 0.f, 0.f}; acc[mf][nf] = zz; }

#pragma unroll
    for (int ks = 0; ks < 8; ++ks) {
        bf16x8 a[4], bb[4];
#pragma unroll
        for (int mf = 0; mf < 4; ++mf)
            a[mf] = *reinterpret_cast<const bf16x8*>(
                kt + (size_t)(row0 + mf * 16 + c) * NH + ks * 32 + g * 8);
#pragma unroll
        for (int nf = 0; nf < 4; ++nf)
            bb[nf] = *reinterpret_cast<const bf16x8*>(
                w_bf + (size_t)(n_base + nf * 16 + c) * NH + ks * 32 + g * 8);
#pragma unroll
        for (int mf = 0; mf < 4; ++mf)
#pragma unroll
            for (int nf = 0; nf < 4; ++nf)
                acc[mf][nf] = __builtin_amdgcn_mfma_f32_16x16x32_bf16(a[mf], bb[nf], acc[mf][nf], 0, 0, 0);
    }

#pragma unroll
    for (int mf = 0; mf < 4; ++mf) {
#pragma unroll
        for (int r = 0; r < 4; ++r) {
            int m = mf * 16 + g * 4 + r;
            int row = row0 + m;
            int bb2 = row / NS;
            float partial = 0.f;
#pragma unroll
            for (int nf = 0; nf < 4; ++nf) {
                int n = n_base + nf * 16 + c;
                float uval = acc[mf][nf][r] + w_bias[n];
                float key = __bfloat162float(kt[(size_t)row * NH + n]) + fmaxf(uval, 0.f);
                partial += key * q[bb2 * NH + n];
            }
            partial += __shfl_xor(partial, 1, 16);
            partial += __shfl_xor(partial, 2, 16);
            partial += __shfl_xor(partial, 4, 16);
            partial += __shfl_xor(partial, 8, 16);
            if (c == 0) sc[wave][m] = partial;
        }
    }
    __syncthreads();
    if (tid < 64) scores[row0 + tid] = sc[0][tid] + sc[1][tid] + sc[2][tid] + sc[3][tid];
}

// ---------------- Kernel 4: softmax over S, aggregate (waves split K), LN5 ----------------
__global__ __launch_bounds__(256) void k_final(
        const float* __restrict__ z, const float* __restrict__ scores,
        const float* __restrict__ p_k_i,
        const float* __restrict__ beta_in, const float* __restrict__ beta_lb,
        const int* __restrict__ flag,
        const float* __restrict__ ln5w, const float* __restrict__ ln5b,
        float* __restrict__ out) {
    __shared__ float p_i[NS];
    __shared__ f32x4 attn4[NS * 4];     // attn[s][k], 4 float4 per s (12.8 KB)
    int tid = threadIdx.x, lane = tid & 63, wave = tid >> 6;
    int b = blockIdx.x;

    if (wave == 0) {
        float l[4]; float mx = -1e30f;
#pragma unroll
        for (int j = 0; j < 4; ++j) {
            int s = lane + 64 * j;
            l[j] = (s < NS) ? scores[b * NS + s] * INV_SQRT_H : -1e30f;
            mx = fmaxf(mx, l[j]);
        }
#pragma unroll
        for (int m = 1; m < 64; m <<= 1) mx = fmaxf(mx, __shfl_xor(mx, m));
        float ev[4]; float se = 0.f;
#pragma unroll
        for (int j = 0; j < 4; ++j) {
            int s = lane + 64 * j;
            ev[j] = (s < NS) ? __expf(l[j] - mx) : 0.f;
            se += ev[j];
        }
        se = wred_sum(se);
        float inv = 1.f / se;
#pragma unroll
        for (int j = 0; j < 4; ++j) {
            int s = lane + 64 * j;
            if (s < NS) p_i[s] = ev[j] * inv;
        }
    }
    __syncthreads();
    for (int idx = tid; idx < NS * 4; idx += 256) {
        f32x4 pk = *reinterpret_cast<const f32x4*>(p_k_i + (size_t)b * NS * NK + idx * 4);
        attn4[idx] = pk * p_i[idx >> 2];
    }
    __syncthreads();

    const float* beta = (*flag) ? beta_in : beta_lb;
    int k0 = wave * 4;
    int h0 = lane * 4;
    f32x4 acc[4];
#pragma unroll
    for (int kk = 0; kk < 4; ++kk)
        acc[kk] = *reinterpret_cast<const f32x4*>(beta + (k0 + kk) * NH + h0);

    const float* zb = z + (size_t)b * NS * NH + h0;
    for (int s = 0; s < NS; ++s) {
        f32x4 zv = *reinterpret_cast<const f32x4*>(zb + s * NH);
        f32x4 at = attn4[s * 4 + wave];
#pragma unroll
        for (int kk = 0; kk < 4; ++kk) acc[kk] += at[kk] * zv;
    }

    f32x4 w5 = *reinterpret_cast<const f32x4*>(ln5w + h0);
    f32x4 b5 = *reinterpret_cast<const f32x4*>(ln5b + h0);
#pragma unroll
    for (int kk = 0; kk < 4; ++kk) {
        float sm = acc[kk][0] + acc[kk][1] + acc[kk][2] + acc[kk][3];
        float sq = acc[kk][0]*acc[kk][0] + acc[kk][1]*acc[kk][1]
                 + acc[kk][2]*acc[kk][2] + acc[kk][3]*acc[kk][3];
        sm = wred_sum(sm); sq = wred_sum(sq);
        float u = sm * (1.f / NH);
        float var = sq * (1.f / NH) - u * u;
        float rstd = rsqrtf(var + EPS_LN);
        f32x4 o;
#pragma unroll
        for (int j = 0; j < 4; ++j) o[j] = w5[j] * (acc[kk][j] - u) * rstd + b5[j];
        *reinterpret_cast<f32x4*>(out + ((size_t)b * NK + k0 + kk) * NH + h0) = o;
    }
}

extern "C" void kernel_launch(void* const* d_in, const int* in_sizes, int n_in,
                              void* d_out, int out_size, void* d_ws, size_t ws_size,
                              hipStream_t stream) {
    const float* z        = (const float*)d_in[0];
    const float* prot     = (const float*)d_in[1];
    const float* ln1w     = (const float*)d_in[2];
    const float* ln1b     = (const float*)d_in[3];
    const float* ln2w     = (const float*)d_in[4];
    const float* ln2b     = (const float*)d_in[5];
    const float* ln3w     = (const float*)d_in[6];
    const float* ln3b     = (const float*)d_in[7];
    const float* ln4w     = (const float*)d_in[8];
    const float* ln4b     = (const float*)d_in[9];
    const float* ln5w     = (const float*)d_in[10];
    const float* ln5b     = (const float*)d_in[11];
    const float* w_weight = (const float*)d_in[12];
    const float* w_bias   = (const float*)d_in[13];
    const float* b_prime  = (const float*)d_in[14];
    const float* alphas   = (const float*)d_in[15];
    const float* beta_in  = (const float*)d_in[16];
    const float* beta_lb  = (const float*)d_in[17];
    const int*   flag     = (const int*)d_in[18];
    float* out = (float*)d_out;

    char* ws = (char*)d_ws;
    float*          pn_div = (float*)(ws);                       // 16 KB
    float*          q      = (float*)(ws + 16384);               // 512 KB
    __hip_bfloat16* w_bf   = (__hip_bfloat16*)(ws + 540672);     // 128 KB
    float*          p_k_i  = (float*)(ws + 671744);              // 6.55 MB
    float*          scores = (float*)(ws + 7225344);             // 410 KB
    __hip_bfloat16* kt     = (__hip_bfloat16*)(ws + 7634944);    // 52.4 MB

    k_prep<<<577, 256, 0, stream>>>(prot, ln2w, ln2b, w_weight, w_bf,
                                    z, b_prime, alphas, ln4w, ln4b, pn_div, q);
    k_rows<<<NB * NS / 4, 256, 0, stream>>>(z, pn_div, ln1w, ln1b, ln3w, ln3b, alphas, p_k_i, kt);
    k_gemm_scores<<<NB * NS / 64, 256, 0, stream>>>(kt, w_bf, w_bias, q, scores);
    k_final<<<NB, 256, 0, stream>>>(z, scores, p_k_i, beta_in, beta_lb, flag, ln5w, ln5b, out);
}

// Round 3
// 349.015 us; speedup vs baseline: 1.2342x; 1.0246x over previous
//
#include <hip/hip_runtime.h>
#include <hip/hip_bf16.h>

#define NB 512
#define NS 200
#define NK 16
#define NH 256
#define INV_SQRT_H 0.0625f
#define EPS_LN 1e-12f
#define EPS_COS 1e-6f

typedef __attribute__((ext_vector_type(8))) short bf16x8;
typedef __attribute__((ext_vector_type(4))) short s16x4;
typedef __attribute__((ext_vector_type(4))) float f32x4;

__device__ __forceinline__ float wred_sum(float v) {
    v += __shfl_xor(v, 1);  v += __shfl_xor(v, 2);  v += __shfl_xor(v, 4);
    v += __shfl_xor(v, 8);  v += __shfl_xor(v, 16); v += __shfl_xor(v, 32);
    return v;
}

__device__ __forceinline__ float red16(float v) {
    v += __shfl_xor(v, 1);  v += __shfl_xor(v, 2);
    v += __shfl_xor(v, 4);  v += __shfl_xor(v, 8);
    return v;
}

__device__ __forceinline__ float block_sum256(float v, float* scr) {
    v = wred_sum(v);
    int w = threadIdx.x >> 6;
    __syncthreads();
    if ((threadIdx.x & 63) == 0) scr[w] = v;
    __syncthreads();
    return scr[0] + scr[1] + scr[2] + scr[3];
}

// ---------------- Kernel 1 (merged prep): protos LN2+norm | cast W | query LN4 ----------------
__global__ __launch_bounds__(256) void k_prep(
        const float* __restrict__ prot, const float* __restrict__ w2, const float* __restrict__ b2,
        const float* __restrict__ w_weight, __hip_bfloat16* __restrict__ w_bf,
        const float* __restrict__ z, const float* __restrict__ b_prime,
        const float* __restrict__ alphas, const float* __restrict__ w4, const float* __restrict__ b4,
        float* __restrict__ pn_div, float* __restrict__ q) {
    __shared__ float scr[4];
    int t = threadIdx.x;
    int bid = blockIdx.x;
    if (bid == 0) {
        for (int k = 0; k < NK; ++k) {
            float x  = prot[k * NH + t];
            float u  = block_sum256(x, scr) * (1.f / NH);
            float d  = x - u;
            float s2 = block_sum256(d * d, scr) * (1.f / NH);
            float pn = w2[t] * d * rsqrtf(s2 + EPS_LN) + b2[t];
            float nsq = block_sum256(pn * pn, scr);
            float pinv = 1.f / fmaxf(sqrtf(nsq), EPS_COS);
            pn_div[k * NH + t] = pn * pinv;
        }
    } else if (bid <= 64) {
        int i = ((bid - 1) * 256 + t) * 4;
        f32x4 w = *reinterpret_cast<const f32x4*>(w_weight + i);
        union { s16x4 v; __hip_bfloat16 h[4]; } u;
#pragma unroll
        for (int j = 0; j < 4; ++j) u.h[j] = __float2bfloat16(w[j]);
        *reinterpret_cast<s16x4*>(w_bf + i) = u.v;
    } else {
        int b = bid - 65;
        float x = b_prime[t] + alphas[(NS - 1) * NH + t] + z[((size_t)b * NS + (NS - 1)) * NH + t];
        float u = block_sum256(x, scr) * (1.f / NH);
        float d = x - u;
        float var = block_sum256(d * d, scr) * (1.f / NH);
        q[b * NH + t] = w4[t] * d * rsqrtf(var + EPS_LN) + b4[t];
    }
}

// ---------------- Kernel 2: per-row pass, 16 lanes per row (4 rows/wave) ----------------
// Outputs: p_k_i, kt (bf16), scores base = dot(keys_tilde, q)
__global__ __launch_bounds__(256) void k_rows(
        const float* __restrict__ z, const float* __restrict__ pn_div,
        const float* __restrict__ ln1w, const float* __restrict__ ln1b,
        const float* __restrict__ ln3w, const float* __restrict__ ln3b,
        const float* __restrict__ alphas, const float* __restrict__ q,
        float* __restrict__ p_k_i, __hip_bfloat16* __restrict__ kt,
        float* __restrict__ scores) {
    int tid = threadIdx.x;
    int c   = tid & 15;                 // lane within 16-group
    int grp = tid >> 4;                 // 16 groups per block
    int row = blockIdx.x * 16 + grp;    // < NB*NS
    int s   = row % NS;
    int b   = row / NS;
    size_t base = (size_t)row * NH;
    int h0 = c * 4;                     // columns h0 + 64*j, j=0..3

    f32x4 zv[4], av[4];
#pragma unroll
    for (int j = 0; j < 4; ++j) {
        zv[j] = *reinterpret_cast<const f32x4*>(z + base + h0 + 64 * j);
        av[j] = *reinterpret_cast<const f32x4*>(alphas + s * NH + h0 + 64 * j);
    }

    // ---- LN1 ----
    float sm = 0.f, sq = 0.f;
#pragma unroll
    for (int j = 0; j < 4; ++j)
#pragma unroll
        for (int i = 0; i < 4; ++i) { sm += zv[j][i]; sq += zv[j][i] * zv[j][i]; }
    sm = red16(sm); sq = red16(sq);
    float u    = sm * (1.f / NH);
    float var  = sq * (1.f / NH) - u * u;
    float rstd = rsqrtf(var + EPS_LN);

    f32x4 zn[4];
    float nsq = 0.f;
#pragma unroll
    for (int j = 0; j < 4; ++j) {
        f32x4 w1 = *reinterpret_cast<const f32x4*>(ln1w + h0 + 64 * j);
        f32x4 b1 = *reinterpret_cast<const f32x4*>(ln1b + h0 + 64 * j);
#pragma unroll
        for (int i = 0; i < 4; ++i) {
            zn[j][i] = w1[i] * (zv[j][i] - u) * rstd + b1[i];
            nsq += zn[j][i] * zn[j][i];
        }
    }
    nsq = red16(nsq);
    float inv_zn = 1.f / fmaxf(sqrtf(nsq), EPS_COS);

    // ---- 16 prototype dot products (per-lane partials over 16 columns) ----
    float acc[NK];
#pragma unroll
    for (int k = 0; k < NK; ++k) {
        float a = 0.f;
#pragma unroll
        for (int j = 0; j < 4; ++j) {
            f32x4 p = *reinterpret_cast<const f32x4*>(pn_div + k * NH + h0 + 64 * j);
            a += zn[j][0]*p[0] + zn[j][1]*p[1] + zn[j][2]*p[2] + zn[j][3]*p[3];
        }
        acc[k] = a;
    }
    // ---- packed butterfly within 16 lanes: lane c ends with total for k = c ----
#pragma unroll
    for (int r = 0; r < 4; ++r) {
        int m = 1 << r;
        int n = NK >> r;
        bool hi = (c & m) != 0;
#pragma unroll
        for (int i = 0; i < 8; ++i) {
            if (i < n / 2) {
                float a = acc[2 * i], bb = acc[2 * i + 1];
                float x = hi ? a : bb;
                float y = __shfl_xor(x, m);
                acc[i] = (hi ? bb : a) + y;
            }
        }
    }

    // ---- softmax over the 16-lane group ----
    float logit = acc[0] * inv_zn * INV_SQRT_H;
    float mx = logit;
    mx = fmaxf(mx, __shfl_xor(mx, 1)); mx = fmaxf(mx, __shfl_xor(mx, 2));
    mx = fmaxf(mx, __shfl_xor(mx, 4)); mx = fmaxf(mx, __shfl_xor(mx, 8));
    float e = __expf(logit - mx);
    float se = e;
    se += __shfl_xor(se, 1); se += __shfl_xor(se, 2);
    se += __shfl_xor(se, 4); se += __shfl_xor(se, 8);
    p_k_i[(size_t)row * NK + c] = e / se;

    // ---- keys_tilde = LN3(z + alphas[s]) -> kt(bf16), plus kt . q ----
    f32x4 xv[4];
    sm = 0.f; sq = 0.f;
#pragma unroll
    for (int j = 0; j < 4; ++j) {
        xv[j] = zv[j] + av[j];
#pragma unroll
        for (int i = 0; i < 4; ++i) { sm += xv[j][i]; sq += xv[j][i] * xv[j][i]; }
    }
    sm = red16(sm); sq = red16(sq);
    float u3 = sm * (1.f / NH);
    float v3 = sq * (1.f / NH) - u3 * u3;
    float r3 = rsqrtf(v3 + EPS_LN);

    float ktq = 0.f;
#pragma unroll
    for (int j = 0; j < 4; ++j) {
        f32x4 w3 = *reinterpret_cast<const f32x4*>(ln3w + h0 + 64 * j);
        f32x4 b3 = *reinterpret_cast<const f32x4*>(ln3b + h0 + 64 * j);
        f32x4 qv = *reinterpret_cast<const f32x4*>(q + b * NH + h0 + 64 * j);
        union { s16x4 v; __hip_bfloat16 h[4]; } kv;
#pragma unroll
        for (int i = 0; i < 4; ++i) {
            float key = w3[i] * (xv[j][i] - u3) * r3 + b3[i];
            kv.h[i] = __float2bfloat16(key);
            ktq += key * qv[i];
        }
        *reinterpret_cast<s16x4*>(kt + base + h0 + 64 * j) = kv.v;
    }
    ktq = red16(ktq);
    if (c == 0) scores[row] = ktq;
}

// ---------------- Kernel 3: MFMA GEMM kt@W^T + relu part of scores ----------------
__global__ __launch_bounds__(256) void k_gemm_scores(
        const __hip_bfloat16* __restrict__ kt, const __hip_bfloat16* __restrict__ w_bf,
        const float* __restrict__ w_bias, const float* __restrict__ q,
        float* __restrict__ scores) {
    __shared__ float sc[4][64];
    int tid = threadIdx.x, wave = tid >> 6, lane = tid & 63;
    int g = lane >> 4, c = lane & 15;
    int row0 = blockIdx.x * 64;
    int n_base = wave * 64;

    f32x4 acc[4][4];
#pragma unroll
    for (int mf = 0; mf < 4; ++mf)
#pragma unroll
        for (int nf = 0; nf < 4; ++nf) { f32x4 zz = {0.f, 0.f, 0.f, 0.f}; acc[mf][nf] = zz; }

#pragma unroll
    for (int ks = 0; ks < 8; ++ks) {
        bf16x8 a[4], bb[4];
#pragma unroll
        for (int mf = 0; mf < 4; ++mf)
            a[mf] = *reinterpret_cast<const bf16x8*>(
                kt + (size_t)(row0 + mf * 16 + c) * NH + ks * 32 + g * 8);
#pragma unroll
        for (int nf = 0; nf < 4; ++nf)
            bb[nf] = *reinterpret_cast<const bf16x8*>(
                w_bf + (size_t)(n_base + nf * 16 + c) * NH + ks * 32 + g * 8);
#pragma unroll
        for (int mf = 0; mf < 4; ++mf)
#pragma unroll
            for (int nf = 0; nf < 4; ++nf)
                acc[mf][nf] = __builtin_amdgcn_mfma_f32_16x16x32_bf16(a[mf], bb[nf], acc[mf][nf], 0, 0, 0);
    }

    // epilogue: relu(u + bias) . q  (kt.q base already in scores)
#pragma unroll
    for (int mf = 0; mf < 4; ++mf) {
#pragma unroll
        for (int r = 0; r < 4; ++r) {
            int m = mf * 16 + g * 4 + r;
            int row = row0 + m;
            int bb2 = row / NS;
            float partial = 0.f;
#pragma unroll
            for (int nf = 0; nf < 4; ++nf) {
                int n = n_base + nf * 16 + c;
                float uval = acc[mf][nf][r] + w_bias[n];
                partial += fmaxf(uval, 0.f) * q[bb2 * NH + n];
            }
            partial += __shfl_xor(partial, 1, 16);
            partial += __shfl_xor(partial, 2, 16);
            partial += __shfl_xor(partial, 4, 16);
            partial += __shfl_xor(partial, 8, 16);
            if (c == 0) sc[wave][m] = partial;
        }
    }
    __syncthreads();
    if (tid < 64)
        scores[row0 + tid] += sc[0][tid] + sc[1][tid] + sc[2][tid] + sc[3][tid];
}

// ---------------- Kernel 4: softmax over S, aggregate (waves split K), LN5 ----------------
__global__ __launch_bounds__(256) void k_final(
        const float* __restrict__ z, const float* __restrict__ scores,
        const float* __restrict__ p_k_i,
        const float* __restrict__ beta_in, const float* __restrict__ beta_lb,
        const int* __restrict__ flag,
        const float* __restrict__ ln5w, const float* __restrict__ ln5b,
        float* __restrict__ out) {
    __shared__ float p_i[NS];
    __shared__ f32x4 attn4[NS * 4];     // attn[s][k], 4 float4 per s (12.8 KB)
    int tid = threadIdx.x, lane = tid & 63, wave = tid >> 6;
    int b = blockIdx.x;

    if (wave == 0) {
        float l[4]; float mx = -1e30f;
#pragma unroll
        for (int j = 0; j < 4; ++j) {
            int s = lane + 64 * j;
            l[j] = (s < NS) ? scores[b * NS + s] * INV_SQRT_H : -1e30f;
            mx = fmaxf(mx, l[j]);
        }
#pragma unroll
        for (int m = 1; m < 64; m <<= 1) mx = fmaxf(mx, __shfl_xor(mx, m));
        float ev[4]; float se = 0.f;
#pragma unroll
        for (int j = 0; j < 4; ++j) {
            int s = lane + 64 * j;
            ev[j] = (s < NS) ? __expf(l[j] - mx) : 0.f;
            se += ev[j];
        }
        se = wred_sum(se);
        float inv = 1.f / se;
#pragma unroll
        for (int j = 0; j < 4; ++j) {
            int s = lane + 64 * j;
            if (s < NS) p_i[s] = ev[j] * inv;
        }
    }
    __syncthreads();
    for (int idx = tid; idx < NS * 4; idx += 256) {
        f32x4 pk = *reinterpret_cast<const f32x4*>(p_k_i + (size_t)b * NS * NK + idx * 4);
        attn4[idx] = pk * p_i[idx >> 2];
    }
    __syncthreads();

    const float* beta = (*flag) ? beta_in : beta_lb;
    int k0 = wave * 4;
    int h0 = lane * 4;
    f32x4 acc[4];
#pragma unroll
    for (int kk = 0; kk < 4; ++kk)
        acc[kk] = *reinterpret_cast<const f32x4*>(beta + (k0 + kk) * NH + h0);

    const float* zb = z + (size_t)b * NS * NH + h0;
    for (int s = 0; s < NS; s += 4) {
        f32x4 zv0 = *reinterpret_cast<const f32x4*>(zb + (s + 0) * NH);
        f32x4 zv1 = *reinterpret_cast<const f32x4*>(zb + (s + 1) * NH);
        f32x4 zv2 = *reinterpret_cast<const f32x4*>(zb + (s + 2) * NH);
        f32x4 zv3 = *reinterpret_cast<const f32x4*>(zb + (s + 3) * NH);
        f32x4 at0 = attn4[(s + 0) * 4 + wave];
        f32x4 at1 = attn4[(s + 1) * 4 + wave];
        f32x4 at2 = attn4[(s + 2) * 4 + wave];
        f32x4 at3 = attn4[(s + 3) * 4 + wave];
#pragma unroll
        for (int kk = 0; kk < 4; ++kk)
            acc[kk] += at0[kk] * zv0 + at1[kk] * zv1 + at2[kk] * zv2 + at3[kk] * zv3;
    }

    f32x4 w5 = *reinterpret_cast<const f32x4*>(ln5w + h0);
    f32x4 b5 = *reinterpret_cast<const f32x4*>(ln5b + h0);
#pragma unroll
    for (int kk = 0; kk < 4; ++kk) {
        float sm = acc[kk][0] + acc[kk][1] + acc[kk][2] + acc[kk][3];
        float sq = acc[kk][0]*acc[kk][0] + acc[kk][1]*acc[kk][1]
                 + acc[kk][2]*acc[kk][2] + acc[kk][3]*acc[kk][3];
        sm = wred_sum(sm); sq = wred_sum(sq);
        float u = sm * (1.f / NH);
        float var = sq * (1.f / NH) - u * u;
        float rstd = rsqrtf(var + EPS_LN);
        f32x4 o;
#pragma unroll
        for (int j = 0; j < 4; ++j) o[j] = w5[j] * (acc[kk][j] - u) * rstd + b5[j];
        *reinterpret_cast<f32x4*>(out + ((size_t)b * NK + k0 + kk) * NH + h0) = o;
    }
}

extern "C" void kernel_launch(void* const* d_in, const int* in_sizes, int n_in,
                              void* d_out, int out_size, void* d_ws, size_t ws_size,
                              hipStream_t stream) {
    const float* z        = (const float*)d_in[0];
    const float* prot     = (const float*)d_in[1];
    const float* ln1w     = (const float*)d_in[2];
    const float* ln1b     = (const float*)d_in[3];
    const float* ln2w     = (const float*)d_in[4];
    const float* ln2b     = (const float*)d_in[5];
    const float* ln3w     = (const float*)d_in[6];
    const float* ln3b     = (const float*)d_in[7];
    const float* ln4w     = (const float*)d_in[8];
    const float* ln4b     = (const float*)d_in[9];
    const float* ln5w     = (const float*)d_in[10];
    const float* ln5b     = (const float*)d_in[11];
    const float* w_weight = (const float*)d_in[12];
    const float* w_bias   = (const float*)d_in[13];
    const float* b_prime  = (const float*)d_in[14];
    const float* alphas   = (const float*)d_in[15];
    const float* beta_in  = (const float*)d_in[16];
    const float* beta_lb  = (const float*)d_in[17];
    const int*   flag     = (const int*)d_in[18];
    float* out = (float*)d_out;

    char* ws = (char*)d_ws;
    float*          pn_div = (float*)(ws);                       // 16 KB
    float*          q      = (float*)(ws + 16384);               // 512 KB
    __hip_bfloat16* w_bf   = (__hip_bfloat16*)(ws + 540672);     // 128 KB
    float*          p_k_i  = (float*)(ws + 671744);              // 6.55 MB
    float*          scores = (float*)(ws + 7225344);             // 410 KB
    __hip_bfloat16* kt     = (__hip_bfloat16*)(ws + 7634944);    // 52.4 MB

    k_prep<<<577, 256, 0, stream>>>(prot, ln2w, ln2b, w_weight, w_bf,
                                    z, b_prime, alphas, ln4w, ln4b, pn_div, q);
    k_rows<<<NB * NS / 16, 256, 0, stream>>>(z, pn_div, ln1w, ln1b, ln3w, ln3b,
                                             alphas, q, p_k_i, kt, scores);
    k_gemm_scores<<<NB * NS / 64, 256, 0, stream>>>(kt, w_bf, w_bias, q, scores);
    k_final<<<NB, 256, 0, stream>>>(z, scores, p_k_i, beta_in, beta_lb, flag, ln5w, ln5b, out);
}